// Round 5
// baseline (351.632 us; speedup 1.0000x reference)
//
#include <hip/hip_runtime.h>
#include <cmath>

// Izhikevich neuron step, N=8192.
// I = w@g + x_in (256 MiB fp32 matvec, memory-bound, HBM floor ~43us)
// then elementwise dynamics; outputs [v_out | spiked_s | u_out | g_out].
//
// R4: persistent multi-row blocks. Grid=1024 (4 blocks/CU), each block
// stages g (32 KiB) into LDS ONCE, then its 4 waves each process 2 rows
// independently (wave-per-row -> shuffle-only reduction, no barriers in
// the row loop). w is streamed with nontemporal f4 loads, 32 per lane
// per row, fully unrolled.

#define NN 8192
#define BLOCK 256
#define GRID 1024                        // 4 blocks/CU
#define ROWS_PER_BLOCK (NN / GRID)       // 8
#define ROWS_PER_WAVE  (ROWS_PER_BLOCK / 4)  // 2

typedef float f4 __attribute__((ext_vector_type(4)));

__global__ __launch_bounds__(BLOCK) void izh_kernel(
    const float* __restrict__ x_in,
    const float* __restrict__ v,
    const float* __restrict__ u,
    const float* __restrict__ g,
    const float* __restrict__ w,
    const float* __restrict__ a_p,
    const float* __restrict__ b_p,
    const float* __restrict__ c_p,
    const float* __restrict__ d_p,
    float* __restrict__ out)
{
    __shared__ f4 g_lds[NN / 4];   // 32 KiB

    const int tid  = threadIdx.x;
    const int lane = tid & 63;
    const int wave = tid >> 6;

    // Stage g into LDS once per block: 2048 f4 / 256 threads = 8 each.
    const f4* g4 = (const f4*)g;
    #pragma unroll
    for (int i = 0; i < (NN / 4) / BLOCK; ++i) {
        g_lds[tid + i * BLOCK] = g4[tid + i * BLOCK];
    }
    __syncthreads();

    // Each wave owns ROWS_PER_WAVE contiguous rows; no barriers below.
    const int row0 = blockIdx.x * ROWS_PER_BLOCK + wave * ROWS_PER_WAVE;

    for (int r = 0; r < ROWS_PER_WAVE; ++r) {
        const int row = row0 + r;
        const f4* w4 = (const f4*)(w + (size_t)row * NN);

        // 2048 f4 / 64 lanes = 32 f4 per lane, fully unrolled so the
        // compiler keeps a deep burst of nontemporal loads in flight.
        float acc0 = 0.0f, acc1 = 0.0f, acc2 = 0.0f, acc3 = 0.0f;
        #pragma unroll
        for (int k = 0; k < 32; ++k) {
            const int idx = lane + 64 * k;
            const f4 wv = __builtin_nontemporal_load(&w4[idx]);
            const f4 gv = g_lds[idx];
            acc0 = fmaf(wv.x, gv.x, acc0);
            acc1 = fmaf(wv.y, gv.y, acc1);
            acc2 = fmaf(wv.z, gv.z, acc2);
            acc3 = fmaf(wv.w, gv.w, acc3);
        }
        float acc = (acc0 + acc1) + (acc2 + acc3);

        // Wave-level reduction (64 lanes), shuffle-only.
        #pragma unroll
        for (int off = 32; off > 0; off >>= 1) {
            acc += __shfl_down(acc, off, 64);
        }

        if (lane == 0) {
            const float I  = acc + x_in[row];
            const float vv = v[row];
            const float uu = u[row];
            const float gg = g[row];

            const float v1 = vv + (0.04f * vv * vv + 5.0f * vv + 140.0f - uu + I);

            // differentiable spike surrogate
            const float s = 1.0f / (1.0f + expf(-4.0f * (v1 - 30.0f)));

            const float spiked = (v1 >= 30.0f) ? 1.0f : 0.0f;
            const float ns     = 1.0f - spiked;

            const float du = fabsf(a_p[row]) * (fabsf(b_p[row]) * v1 - uu);
            const float dg = -gg / 6.5f;

            out[0 * NN + row] = ns * v1 + spiked * c_p[row];        // v_out
            out[1 * NN + row] = s;                                  // spiked_s
            out[2 * NN + row] = ns * (uu + du) + spiked * d_p[row]; // u_out
            out[3 * NN + row] = ns * (gg + dg) + spiked;            // g_out
        }
    }
}

extern "C" void kernel_launch(void* const* d_in, const int* in_sizes, int n_in,
                              void* d_out, int out_size, void* d_ws, size_t ws_size,
                              hipStream_t stream) {
    // setup_inputs() order: x_in, v, u, g, w, a_p, b_p, c_p, d_p
    const float* x_in = (const float*)d_in[0];
    const float* v    = (const float*)d_in[1];
    const float* u    = (const float*)d_in[2];
    const float* g    = (const float*)d_in[3];
    const float* w    = (const float*)d_in[4];
    const float* a_p  = (const float*)d_in[5];
    const float* b_p  = (const float*)d_in[6];
    const float* c_p  = (const float*)d_in[7];
    const float* d_p  = (const float*)d_in[8];
    float* out = (float*)d_out;

    izh_kernel<<<GRID, BLOCK, 0, stream>>>(x_in, v, u, g, w, a_p, b_p, c_p, d_p, out);
}